// Round 1
// baseline (833.859 us; speedup 1.0000x reference)
//
#include <hip/hip_runtime.h>
#include <math.h>

#define BS 2
#define SEQ 1024
#define DM 512
#define NH 8
#define DK 64
#define MAXN 5

// ---------------- LayerNorm: one block per row of q ----------------
__global__ void ln_kernel(const float* __restrict__ q, float* __restrict__ qn,
                          const float* __restrict__ gamma, const float* __restrict__ beta) {
    int row = blockIdx.x;               // 0..2047
    const float* x = q + (size_t)row * DM;
    float* y = qn + (size_t)row * DM;
    int tid = threadIdx.x;              // 256 threads
    float v1 = x[tid], v2 = x[tid + 256];
    float s = v1 + v2;
    float ss = v1 * v1 + v2 * v2;
    for (int o = 32; o > 0; o >>= 1) { s += __shfl_down(s, o); ss += __shfl_down(ss, o); }
    __shared__ float red[4], red2[4];
    __shared__ float s_mu, s_rstd;
    int wid = tid >> 6, lane = tid & 63;
    if (lane == 0) { red[wid] = s; red2[wid] = ss; }
    __syncthreads();
    if (tid == 0) {
        float ts = red[0] + red[1] + red[2] + red[3];
        float tss = red2[0] + red2[1] + red2[2] + red2[3];
        float mu = ts / DM;
        float var = tss / DM - mu * mu;
        s_mu = mu;
        s_rstd = rsqrtf(var + 1e-6f);
    }
    __syncthreads();
    float mu = s_mu, rstd = s_rstd;
    y[tid]       = (v1 - mu) * rstd * gamma[tid]       + beta[tid];
    y[tid + 256] = (v2 - mu) * rstd * gamma[tid + 256] + beta[tid + 256];
}

// ---------------- Simple f32 tiled GEMM: C[M,N] = A[M,K] @ B[K,N] * scale (+Rsd) ----------------
template<bool RES>
__global__ void gemm_kernel(const float* __restrict__ A, const float* __restrict__ B,
                            const float* __restrict__ Rsd, float* __restrict__ C,
                            int M, int N, int K, float scale) {
    __shared__ float As[64][17];
    __shared__ float Bs[16][65];
    int tid = threadIdx.x;              // 256
    int nbx = N >> 6;
    int bx = blockIdx.x % nbx, by = blockIdx.x / nbx;
    int row0 = by * 64, col0 = bx * 64;
    int tx = tid & 15, ty = tid >> 4;   // 16x16 thread grid, 4x4 micro-tile
    float acc[4][4] = {};
    for (int k0 = 0; k0 < K; k0 += 16) {
        for (int idx = tid; idx < 64 * 16; idx += 256) {
            int r = idx >> 4, c = idx & 15;
            As[r][c] = A[(size_t)(row0 + r) * K + k0 + c];
        }
        {
            int r = tid >> 6, c = tid & 63;
            #pragma unroll
            for (int rr = 0; rr < 4; ++rr)
                Bs[r + rr * 4][c] = B[(size_t)(k0 + r + rr * 4) * N + col0 + c];
        }
        __syncthreads();
        #pragma unroll
        for (int kk = 0; kk < 16; ++kk) {
            float a[4], b[4];
            #pragma unroll
            for (int i = 0; i < 4; ++i) a[i] = As[ty * 4 + i][kk];
            #pragma unroll
            for (int j = 0; j < 4; ++j) b[j] = Bs[kk][tx * 4 + j];
            #pragma unroll
            for (int i = 0; i < 4; ++i)
                #pragma unroll
                for (int j = 0; j < 4; ++j)
                    acc[i][j] += a[i] * b[j];
        }
        __syncthreads();
    }
    #pragma unroll
    for (int i = 0; i < 4; ++i) {
        int r = row0 + ty * 4 + i;
        #pragma unroll
        for (int j = 0; j < 4; ++j) {
            int c = col0 + tx * 4 + j;
            float v = acc[i][j] * scale;
            if (RES) v += Rsd[(size_t)r * N + c];
            C[(size_t)r * N + c] = v;
        }
    }
}

// ---------------- Attention: one block per (b,h,i) row ----------------
__global__ void attn_kernel(const float* __restrict__ qs,   // [b,i,h*64+d] already /8
                            const float* __restrict__ kh,   // [b,j,h*64+d]
                            const float* __restrict__ vh,   // [b,j,h*64+d]
                            const int* __restrict__ mask,   // [b,i,j]
                            const int* __restrict__ dist,   // [b,i,j]
                            const float* __restrict__ rpr,  // [6,64]
                            float* __restrict__ attn_out,   // [b,h,i,j]
                            float* __restrict__ oh)         // [b,i,h*64+d]
{
    int blk = blockIdx.x;               // (b*8+h)*1024 + i
    int i = blk & 1023;
    int bh = blk >> 10;
    int h = bh & 7;
    int b = bh >> 3;
    int tid = threadIdx.x;              // 256

    __shared__ float sQ[64];
    __shared__ float sQB[6];
    __shared__ float sP[SEQ];
    __shared__ float sRed[4];
    __shared__ float sOut[4][64];

    const float* qrow = qs + ((size_t)(b * SEQ + i) * DM + h * 64);
    if (tid < 64) sQ[tid] = qrow[tid];
    __syncthreads();
    if (tid < 64) {
        float qv = sQ[tid];
        #pragma unroll
        for (int m = 0; m < 6; ++m) {
            float p = qv * rpr[m * 64 + tid];
            for (int o = 32; o > 0; o >>= 1) p += __shfl_down(p, o);
            if (tid == 0) sQB[m] = p;
        }
    }
    __syncthreads();

    const float* kbase = kh + (size_t)b * SEQ * DM + h * 64;
    const int* mrow = mask + (size_t)(b * SEQ + i) * SEQ;
    const int* drow = dist + (size_t)(b * SEQ + i) * SEQ;

    float lmax = -1e30f;
    for (int j = tid; j < SEQ; j += 256) {
        const float* krow = kbase + (size_t)j * DM;
        float dot = 0.f;
        #pragma unroll
        for (int d = 0; d < 64; d += 4) {
            float4 kv = *reinterpret_cast<const float4*>(krow + d);
            dot += sQ[d] * kv.x + sQ[d + 1] * kv.y + sQ[d + 2] * kv.z + sQ[d + 3] * kv.w;
        }
        int dc = drow[j]; dc = dc > MAXN ? MAXN : dc;
        float s = dot + sQB[dc];
        if (mrow[j] == 0) s = -1e9f;
        sP[j] = s;
        lmax = fmaxf(lmax, s);
    }
    for (int o = 32; o > 0; o >>= 1) lmax = fmaxf(lmax, __shfl_down(lmax, o));
    int wid = tid >> 6, lane = tid & 63;
    if (lane == 0) sRed[wid] = lmax;
    __syncthreads();
    float gmax = fmaxf(fmaxf(sRed[0], sRed[1]), fmaxf(sRed[2], sRed[3]));
    float lsum = 0.f;
    for (int j = tid; j < SEQ; j += 256) {
        float p = __expf(sP[j] - gmax);
        sP[j] = p;
        lsum += p;
    }
    for (int o = 32; o > 0; o >>= 1) lsum += __shfl_down(lsum, o);
    __syncthreads();
    if (lane == 0) sRed[wid] = lsum;
    __syncthreads();
    float rsum = 1.f / (sRed[0] + sRed[1] + sRed[2] + sRed[3]);

    float* arow = attn_out + ((size_t)bh * SEQ + i) * SEQ;
    for (int j = tid; j < SEQ; j += 256) {
        float p = sP[j] * rsum;
        sP[j] = p;
        arow[j] = p;
    }
    __syncthreads();

    int d = tid & 63, c = tid >> 6;
    const float* vbase = vh + (size_t)b * SEQ * DM + h * 64;
    float acc = 0.f;
    for (int j = c * 256; j < (c + 1) * 256; ++j) {
        acc += sP[j] * vbase[(size_t)j * DM + d];
    }
    sOut[c][d] = acc;
    __syncthreads();
    if (tid < 64) {
        float o = sOut[0][tid] + sOut[1][tid] + sOut[2][tid] + sOut[3][tid];
        oh[(size_t)(b * SEQ + i) * DM + h * 64 + tid] = o;
    }
}

extern "C" void kernel_launch(void* const* d_in, const int* in_sizes, int n_in,
                              void* d_out, int out_size, void* d_ws, size_t ws_size,
                              hipStream_t stream) {
    const float* q     = (const float*)d_in[0];
    const float* k     = (const float*)d_in[1];
    const float* v     = (const float*)d_in[2];
    const int*   mask  = (const int*)d_in[3];
    const int*   dist  = (const int*)d_in[4];
    const float* w_qs  = (const float*)d_in[5];
    const float* w_ks  = (const float*)d_in[6];
    const float* w_vs  = (const float*)d_in[7];
    const float* w_fc  = (const float*)d_in[8];
    const float* gamma = (const float*)d_in[9];
    const float* beta  = (const float*)d_in[10];
    const float* rpr   = (const float*)d_in[11];

    float* ws  = (float*)d_ws;
    float* qn  = ws;                       // 2048*512 (reused as oh after q-proj)
    float* qsb = ws + 1 * 1048576;
    float* khb = ws + 2 * 1048576;
    float* vhb = ws + 3 * 1048576;
    float* oh  = qn;

    float* outp  = (float*)d_out;          // [2,1024,512]
    float* attnp = outp + 1048576;         // [2,8,1024,1024]

    ln_kernel<<<2048, 256, 0, stream>>>(q, qn, gamma, beta);
    gemm_kernel<false><<<256, 256, 0, stream>>>(qn, w_qs, nullptr, qsb, 2048, 512, 512, 0.125f);
    gemm_kernel<false><<<256, 256, 0, stream>>>(k,  w_ks, nullptr, khb, 2048, 512, 512, 1.0f);
    gemm_kernel<false><<<256, 256, 0, stream>>>(v,  w_vs, nullptr, vhb, 2048, 512, 512, 1.0f);
    attn_kernel<<<BS * NH * SEQ, 256, 0, stream>>>(qsb, khb, vhb, mask, dist, rpr, attnp, oh);
    gemm_kernel<true><<<256, 256, 0, stream>>>(oh, w_fc, q, outp, 2048, 512, 512, 1.0f);
}

// Round 2
// 125.100 us; speedup vs baseline: 6.6655x; 6.6655x over previous
//
#include <hip/hip_runtime.h>
#include <math.h>

#define SEQ 1024
#define DM 512

typedef __attribute__((ext_vector_type(8))) short bf16x8;
typedef __attribute__((ext_vector_type(4))) short bf16x4;
typedef __attribute__((ext_vector_type(4))) float f32x4;

static __device__ __forceinline__ short f2b(float f) {
    union { float f; unsigned u; } x; x.f = f;
    unsigned r = (x.u + 0x7FFFu + ((x.u >> 16) & 1u)) >> 16;
    return (short)r;
}
static __device__ __forceinline__ float b2f(short s) {
    union { unsigned u; float f; } x; x.u = ((unsigned)(unsigned short)s) << 16;
    return x.f;
}
// swizzled elem index into a [64][64] bf16 LDS tile (128B rows, XOR bank swizzle)
static __device__ __forceinline__ int sidx(int row, int col) {
    int byte = (row << 7) + (col << 1);
    byte ^= (row & 7) << 4;
    return byte >> 1;
}

// stage a 64x64 tile into swizzled bf16 LDS; 256 threads, thread t: row t>>2, cols (t&3)*16..+15
static __device__ __forceinline__ void stage_f32(short* dst, const float* src, int srcStride, int tid) {
    int r = tid >> 2, c = (tid & 3) * 16;
    const float* p = src + (size_t)r * srcStride + c;
    bf16x8 v0, v1;
    #pragma unroll
    for (int e = 0; e < 8; ++e) v0[e] = f2b(p[e]);
    #pragma unroll
    for (int e = 0; e < 8; ++e) v1[e] = f2b(p[8 + e]);
    *(bf16x8*)&dst[sidx(r, c)] = v0;
    *(bf16x8*)&dst[sidx(r, c + 8)] = v1;
}
static __device__ __forceinline__ void stage_bf16(short* dst, const short* src, int srcStride, int tid) {
    int r = tid >> 2, c = (tid & 3) * 16;
    const short* p = src + (size_t)r * srcStride + c;
    bf16x8 v0 = *(const bf16x8*)p;
    bf16x8 v1 = *(const bf16x8*)(p + 8);
    *(bf16x8*)&dst[sidx(r, c)] = v0;
    *(bf16x8*)&dst[sidx(r, c + 8)] = v1;
}

// ---------------- LayerNorm ----------------
__global__ __launch_bounds__(256) void ln_kernel(const float* __restrict__ q, float* __restrict__ qn,
                          const float* __restrict__ gamma, const float* __restrict__ beta) {
    int row = blockIdx.x;
    const float* x = q + (size_t)row * DM;
    float* y = qn + (size_t)row * DM;
    int tid = threadIdx.x;
    float v1 = x[tid], v2 = x[tid + 256];
    float s = v1 + v2;
    float ss = v1 * v1 + v2 * v2;
    for (int o = 32; o > 0; o >>= 1) { s += __shfl_down(s, o); ss += __shfl_down(ss, o); }
    __shared__ float red[4], red2[4];
    __shared__ float s_mu, s_rstd;
    int wid = tid >> 6, lane = tid & 63;
    if (lane == 0) { red[wid] = s; red2[wid] = ss; }
    __syncthreads();
    if (tid == 0) {
        float ts = red[0] + red[1] + red[2] + red[3];
        float tss = red2[0] + red2[1] + red2[2] + red2[3];
        float mu = ts / DM;
        float var = tss / DM - mu * mu;
        s_mu = mu;
        s_rstd = rsqrtf(var + 1e-6f);
    }
    __syncthreads();
    float mu = s_mu, rstd = s_rstd;
    y[tid]       = (v1 - mu) * rstd * gamma[tid]       + beta[tid];
    y[tid + 256] = (v2 - mu) * rstd * gamma[tid + 256] + beta[tid + 256];
}

// ---------------- weight transpose+convert: 4x [512K][512N] f32 -> [N][K] bf16 ----------------
__global__ __launch_bounds__(256) void wtrans_kernel(const float* __restrict__ w0, const float* __restrict__ w1,
        const float* __restrict__ w2, const float* __restrict__ w3, short* __restrict__ wt) {
    int blk = blockIdx.x;
    int wsel = blk >> 6;
    int t = blk & 63;
    int tr = t >> 3, tc = t & 7;
    const float* src = wsel == 0 ? w0 : wsel == 1 ? w1 : wsel == 2 ? w2 : w3;
    short* dst = wt + (size_t)wsel * 512 * 512;
    __shared__ float tile[64][65];
    int r = threadIdx.x >> 2, c = (threadIdx.x & 3) * 16;
    const float* p = src + (size_t)(tr * 64 + r) * 512 + tc * 64 + c;
    #pragma unroll
    for (int e = 0; e < 16; ++e) tile[r][c + e] = p[e];
    __syncthreads();
    bf16x8 v0, v1;
    #pragma unroll
    for (int e = 0; e < 16; ++e) {
        short bv = f2b(tile[c + e][r]);
        if (e < 8) v0[e] = bv; else v1[e - 8] = bv;
    }
    short* qd = dst + (size_t)(tc * 64 + r) * 512 + tr * 64 + c;
    *(bf16x8*)qd = v0;
    *(bf16x8*)(qd + 8) = v1;
}

// ---------------- MFMA GEMM: C[M,N] = A[M,K] @ Bt[N,K]^T ----------------
// MODE 0: f32 out + residual; MODE 1: bf16 out; MODE 2: bf16 transposed vT out [bh][64][1024]
template<int MODE, bool ABF>
__global__ __launch_bounds__(256) void mgemm(const void* __restrict__ Ap, const short* __restrict__ Bt,
                                             const float* __restrict__ Rsd, void* __restrict__ Cp,
                                             int M, int N, int K, float scale) {
    __shared__ short sA[64 * 64];
    __shared__ short sB[64 * 64];
    int tid = threadIdx.x;
    int nbx = N >> 6;
    int bx = blockIdx.x % nbx, by = blockIdx.x / nbx;
    int m0 = by << 6, n0 = bx << 6;
    int w = tid >> 6, l = tid & 63;
    int lr = l & 15, lg = l >> 4;
    f32x4 acc[4] = {};
    for (int kt = 0; kt < K; kt += 64) {
        __syncthreads();
        if (ABF) stage_bf16(sA, (const short*)Ap + (size_t)m0 * K + kt, K, tid);
        else     stage_f32 (sA, (const float*)Ap + (size_t)m0 * K + kt, K, tid);
        stage_bf16(sB, Bt + (size_t)n0 * K + kt, K, tid);
        __syncthreads();
        #pragma unroll
        for (int ks = 0; ks < 2; ++ks) {
            bf16x8 af = *(const bf16x8*)&sA[sidx(w * 16 + lr, ks * 32 + lg * 8)];
            #pragma unroll
            for (int nt = 0; nt < 4; ++nt) {
                bf16x8 bf = *(const bf16x8*)&sB[sidx(nt * 16 + lr, ks * 32 + lg * 8)];
                acc[nt] = __builtin_amdgcn_mfma_f32_16x16x32_bf16(af, bf, acc[nt], 0, 0, 0);
            }
        }
    }
    if (MODE == 2) {
        #pragma unroll
        for (int nt = 0; nt < 4; ++nt) {
            int gn = n0 + nt * 16 + lr;
            int gm0 = m0 + w * 16 + lg * 4;
            int bq = gm0 >> 10, j0 = gm0 & 1023;
            int h = gn >> 6, dl = gn & 63;
            bf16x4 pk;
            #pragma unroll
            for (int r = 0; r < 4; ++r) pk[r] = f2b(acc[nt][r] * scale);
            *(bf16x4*)&((short*)Cp)[(((size_t)((bq << 3) + h) << 6) + dl) * 1024 + j0] = pk;
        }
    } else {
        #pragma unroll
        for (int nt = 0; nt < 4; ++nt) {
            #pragma unroll
            for (int r = 0; r < 4; ++r) {
                int gm = m0 + w * 16 + lg * 4 + r;
                int gn = n0 + nt * 16 + lr;
                float v = acc[nt][r] * scale;
                if (MODE == 0) {
                    v += Rsd[(size_t)gm * N + gn];
                    ((float*)Cp)[(size_t)gm * N + gn] = v;
                } else {
                    ((short*)Cp)[(size_t)gm * N + gn] = f2b(v);
                }
            }
        }
    }
}

// ---------------- attention pass 1: S = QK^T + bias (masked), write raw S, track m,l ----------------
__global__ __launch_bounds__(256) void attn_score_kernel(
    const short* __restrict__ qsb, const short* __restrict__ khb,
    const int* __restrict__ mask, const int* __restrict__ dist,
    const float* __restrict__ rpr, float* __restrict__ S,
    float* __restrict__ mbuf, float* __restrict__ lbuf) {
    int bh = blockIdx.x >> 4;
    int it = blockIdx.x & 15;
    int b = bh >> 3, h = bh & 7;
    int i0 = it << 6;
    int tid = threadIdx.x;
    int w = tid >> 6, l = tid & 63;
    int lr = l & 15, lg = l >> 4;

    __shared__ short sQ[64 * 64];
    __shared__ short sK[64 * 64];
    __shared__ float sQB[64 * 8];

    stage_bf16(sQ, qsb + ((size_t)(b * SEQ + i0)) * DM + h * 64, DM, tid);
    __syncthreads();
    {
        int r = tid >> 2, mm = tid & 3;
        for (int m = mm; m < 6; m += 4) {
            float a = 0.f;
            for (int d = 0; d < 64; ++d) a += b2f(sQ[sidx(r, d)]) * rpr[m * 64 + d];
            sQB[r * 8 + m] = a;
        }
    }
    __syncthreads();

    bf16x8 qf[2];
    qf[0] = *(const bf16x8*)&sQ[sidx(w * 16 + lr, lg * 8)];
    qf[1] = *(const bf16x8*)&sQ[sidx(w * 16 + lr, 32 + lg * 8)];

    float m_run[4], l_run[4];
    #pragma unroll
    for (int r = 0; r < 4; ++r) { m_run[r] = -1e30f; l_run[r] = 0.f; }

    for (int jt = 0; jt < 16; ++jt) {
        __syncthreads();
        stage_bf16(sK, khb + ((size_t)(b * SEQ + jt * 64)) * DM + h * 64, DM, tid);
        __syncthreads();
        f32x4 sf[4] = {};
        #pragma unroll
        for (int ks = 0; ks < 2; ++ks) {
            bf16x8 a = qf[ks];
            #pragma unroll
            for (int nt = 0; nt < 4; ++nt) {
                bf16x8 kf = *(const bf16x8*)&sK[sidx(nt * 16 + lr, ks * 32 + lg * 8)];
                sf[nt] = __builtin_amdgcn_mfma_f32_16x16x32_bf16(a, kf, sf[nt], 0, 0, 0);
            }
        }
        #pragma unroll
        for (int nt = 0; nt < 4; ++nt) {
            int gj = jt * 64 + nt * 16 + lr;
            #pragma unroll
            for (int r = 0; r < 4; ++r) {
                int il = w * 16 + lg * 4 + r;
                int gi = i0 + il;
                size_t gidx = ((size_t)(b * SEQ + gi)) * SEQ + gj;
                int dd = dist[gidx];
                dd = dd > 5 ? 5 : dd;
                float s = sf[nt][r] + sQB[il * 8 + dd];
                if (mask[gidx] == 0) s = -1e9f;
                sf[nt][r] = s;
                S[((size_t)(bh * SEQ + gi)) * SEQ + gj] = s;
            }
        }
        #pragma unroll
        for (int r = 0; r < 4; ++r) {
            float mx = fmaxf(fmaxf(sf[0][r], sf[1][r]), fmaxf(sf[2][r], sf[3][r]));
            mx = fmaxf(mx, __shfl_xor(mx, 1));
            mx = fmaxf(mx, __shfl_xor(mx, 2));
            mx = fmaxf(mx, __shfl_xor(mx, 4));
            mx = fmaxf(mx, __shfl_xor(mx, 8));
            float mnew = fmaxf(m_run[r], mx);
            float sum = __expf(sf[0][r] - mnew) + __expf(sf[1][r] - mnew)
                      + __expf(sf[2][r] - mnew) + __expf(sf[3][r] - mnew);
            sum += __shfl_xor(sum, 1);
            sum += __shfl_xor(sum, 2);
            sum += __shfl_xor(sum, 4);
            sum += __shfl_xor(sum, 8);
            l_run[r] = l_run[r] * __expf(m_run[r] - mnew) + sum;
            m_run[r] = mnew;
        }
    }
    if (lr == 0) {
        #pragma unroll
        for (int r = 0; r < 4; ++r) {
            int gi = i0 + w * 16 + lg * 4 + r;
            mbuf[bh * SEQ + gi] = m_run[r];
            lbuf[bh * SEQ + gi] = l_run[r];
        }
    }
}

// ---------------- attention pass 2: P = exp(S-m)/l (write attn), O = P @ V ----------------
__global__ __launch_bounds__(256) void attn_pv_kernel(
    float* __restrict__ S, const float* __restrict__ mbuf, const float* __restrict__ lbuf,
    const short* __restrict__ vT, short* __restrict__ oh) {
    int bh = blockIdx.x >> 4;
    int it = blockIdx.x & 15;
    int b = bh >> 3, h = bh & 7;
    int i0 = it << 6;
    int tid = threadIdx.x;
    int w = tid >> 6, l = tid & 63;
    int lr = l & 15, lg = l >> 4;
    __shared__ short sP[64 * 64];
    __shared__ short sV[64 * 64];

    int sr = tid >> 2, sc = (tid & 3) * 16;
    float mrow = mbuf[bh * SEQ + i0 + sr];
    float rl = 1.f / lbuf[bh * SEQ + i0 + sr];
    float* Srow = S + ((size_t)(bh * SEQ + i0 + sr)) * SEQ + sc;
    const short* vrow = vT + ((size_t)(bh * 64 + sr)) * SEQ + sc;

    f32x4 oacc[4] = {};
    for (int jt = 0; jt < 16; ++jt) {
        __syncthreads();
        {
            float* p = Srow + jt * 64;
            bf16x8 v0, v1;
            #pragma unroll
            for (int e = 0; e < 16; ++e) {
                float pv = __expf(p[e] - mrow) * rl;
                p[e] = pv;
                if (e < 8) v0[e] = f2b(pv); else v1[e - 8] = f2b(pv);
            }
            *(bf16x8*)&sP[sidx(sr, sc)] = v0;
            *(bf16x8*)&sP[sidx(sr, sc + 8)] = v1;
            const short* vq = vrow + jt * 64;
            *(bf16x8*)&sV[sidx(sr, sc)] = *(const bf16x8*)vq;
            *(bf16x8*)&sV[sidx(sr, sc + 8)] = *(const bf16x8*)(vq + 8);
        }
        __syncthreads();
        #pragma unroll
        for (int ks = 0; ks < 2; ++ks) {
            bf16x8 pf = *(const bf16x8*)&sP[sidx(w * 16 + lr, ks * 32 + lg * 8)];
            #pragma unroll
            for (int nt = 0; nt < 4; ++nt) {
                bf16x8 vf = *(const bf16x8*)&sV[sidx(nt * 16 + lr, ks * 32 + lg * 8)];
                oacc[nt] = __builtin_amdgcn_mfma_f32_16x16x32_bf16(pf, vf, oacc[nt], 0, 0, 0);
            }
        }
    }
    #pragma unroll
    for (int nt = 0; nt < 4; ++nt) {
        #pragma unroll
        for (int r = 0; r < 4; ++r) {
            int gi = i0 + w * 16 + lg * 4 + r;
            int gd = nt * 16 + lr;
            oh[((size_t)(b * SEQ + gi)) * DM + h * 64 + gd] = f2b(oacc[nt][r]);
        }
    }
}

extern "C" void kernel_launch(void* const* d_in, const int* in_sizes, int n_in,
                              void* d_out, int out_size, void* d_ws, size_t ws_size,
                              hipStream_t stream) {
    const float* q     = (const float*)d_in[0];
    const float* k     = (const float*)d_in[1];
    const float* v     = (const float*)d_in[2];
    const int*   mask  = (const int*)d_in[3];
    const int*   dist  = (const int*)d_in[4];
    const float* w_qs  = (const float*)d_in[5];
    const float* w_ks  = (const float*)d_in[6];
    const float* w_vs  = (const float*)d_in[7];
    const float* w_fc  = (const float*)d_in[8];
    const float* gamma = (const float*)d_in[9];
    const float* beta  = (const float*)d_in[10];
    const float* rpr   = (const float*)d_in[11];

    float* ws   = (float*)d_ws;
    float* qn   = ws;                                   // [0, 1M) f32
    short* wT   = (short*)(ws + 1048576);               // 4 x 512x512 bf16
    short* qsb  = (short*)(ws + 1048576 + 524288);      // 2048x512 bf16
    short* khb  = qsb + 2048 * 512;
    short* vT   = khb + 2048 * 512;                     // [16][64][1024] bf16
    float* mbuf = (float*)(vT + 16 * 64 * 1024);
    float* lbuf = mbuf + 16384;
    short* oh   = (short*)qn;                           // reuse qn region after q-proj

    float* outp  = (float*)d_out;
    float* attnp = outp + 1048576;

    wtrans_kernel<<<256, 256, 0, stream>>>(w_qs, w_ks, w_vs, w_fc, wT);
    ln_kernel<<<2048, 256, 0, stream>>>(q, qn, gamma, beta);
    mgemm<1, false><<<256, 256, 0, stream>>>(qn, wT,          nullptr, qsb, 2048, 512, 512, 0.125f);
    mgemm<1, false><<<256, 256, 0, stream>>>(k,  wT + 262144, nullptr, khb, 2048, 512, 512, 1.0f);
    mgemm<2, false><<<256, 256, 0, stream>>>(v,  wT + 524288, nullptr, vT,  2048, 512, 512, 1.0f);
    attn_score_kernel<<<256, 256, 0, stream>>>(qsb, khb, mask, dist, rpr, attnp, mbuf, lbuf);
    attn_pv_kernel<<<256, 256, 0, stream>>>(attnp, mbuf, lbuf, vT, oh);
    mgemm<0, true><<<256, 256, 0, stream>>>(oh, wT + 786432, q, outp, 2048, 512, 512, 1.0f);
}

// Round 3
// 118.953 us; speedup vs baseline: 7.0100x; 1.0517x over previous
//
#include <hip/hip_runtime.h>
#include <math.h>

#define SEQ 1024
#define DM 512

typedef __attribute__((ext_vector_type(8))) short bf16x8;
typedef __attribute__((ext_vector_type(4))) short bf16x4;
typedef __attribute__((ext_vector_type(4))) float f32x4;
typedef __attribute__((ext_vector_type(4))) int i32x4;

static __device__ __forceinline__ short f2b(float f) {
    union { float f; unsigned u; } x; x.f = f;
    unsigned r = (x.u + 0x7FFFu + ((x.u >> 16) & 1u)) >> 16;
    return (short)r;
}
static __device__ __forceinline__ float b2f(short s) {
    union { unsigned u; float f; } x; x.u = ((unsigned)(unsigned short)s) << 16;
    return x.f;
}
// swizzled elem index into a [64][64] bf16 LDS tile (128B rows, XOR bank swizzle)
static __device__ __forceinline__ int sidx(int row, int col) {
    int byte = (row << 7) + (col << 1);
    byte ^= (row & 7) << 4;
    return byte >> 1;
}

static __device__ __forceinline__ void stage_f32(short* dst, const float* src, int srcStride, int tid) {
    int r = tid >> 2, c = (tid & 3) * 16;
    const float* p = src + (size_t)r * srcStride + c;
    bf16x8 v0, v1;
    #pragma unroll
    for (int e = 0; e < 8; ++e) v0[e] = f2b(p[e]);
    #pragma unroll
    for (int e = 0; e < 8; ++e) v1[e] = f2b(p[8 + e]);
    *(bf16x8*)&dst[sidx(r, c)] = v0;
    *(bf16x8*)&dst[sidx(r, c + 8)] = v1;
}
static __device__ __forceinline__ void stage_bf16(short* dst, const short* src, int srcStride, int tid) {
    int r = tid >> 2, c = (tid & 3) * 16;
    const short* p = src + (size_t)r * srcStride + c;
    bf16x8 v0 = *(const bf16x8*)p;
    bf16x8 v1 = *(const bf16x8*)(p + 8);
    *(bf16x8*)&dst[sidx(r, c)] = v0;
    *(bf16x8*)&dst[sidx(r, c + 8)] = v1;
}

// 64x64x64 MFMA block: acc[nt] over rows w*16.., cols nt*16..
static __device__ __forceinline__ void mma64(const short* sA, const short* sB, f32x4* acc,
                                             int w, int lr, int lg) {
    #pragma unroll
    for (int ks = 0; ks < 2; ++ks) {
        bf16x8 af = *(const bf16x8*)&sA[sidx(w * 16 + lr, ks * 32 + lg * 8)];
        #pragma unroll
        for (int nt = 0; nt < 4; ++nt) {
            bf16x8 bf = *(const bf16x8*)&sB[sidx(nt * 16 + lr, ks * 32 + lg * 8)];
            acc[nt] = __builtin_amdgcn_mfma_f32_16x16x32_bf16(af, bf, acc[nt], 0, 0, 0);
        }
    }
}

// ---------------- prep: wtrans (256 blk) + layernorm (2048 blk) + idx pack (2048 blk) ----------------
__global__ __launch_bounds__(256) void prep_kernel(
    const float* __restrict__ w0, const float* __restrict__ w1,
    const float* __restrict__ w2, const float* __restrict__ w3, short* __restrict__ wt,
    const float* __restrict__ q, float* __restrict__ qn,
    const float* __restrict__ gamma, const float* __restrict__ beta,
    const int* __restrict__ dist, const int* __restrict__ mask, unsigned char* __restrict__ idxp) {
    int blk = blockIdx.x;
    int tid = threadIdx.x;
    if (blk < 256) {
        int wsel = blk >> 6;
        int t = blk & 63;
        int tr = t >> 3, tc = t & 7;
        const float* src = wsel == 0 ? w0 : wsel == 1 ? w1 : wsel == 2 ? w2 : w3;
        short* dst = wt + (size_t)wsel * 512 * 512;
        __shared__ float tile[64][65];
        int r = tid >> 2, c = (tid & 3) * 16;
        const float* p = src + (size_t)(tr * 64 + r) * 512 + tc * 64 + c;
        #pragma unroll
        for (int e = 0; e < 16; ++e) tile[r][c + e] = p[e];
        __syncthreads();
        bf16x8 v0, v1;
        #pragma unroll
        for (int e = 0; e < 16; ++e) {
            short bv = f2b(tile[c + e][r]);
            if (e < 8) v0[e] = bv; else v1[e - 8] = bv;
        }
        short* qd = dst + (size_t)(tc * 64 + r) * 512 + tr * 64 + c;
        *(bf16x8*)qd = v0;
        *(bf16x8*)(qd + 8) = v1;
    } else if (blk < 2304) {
        int row = blk - 256;
        const float* x = q + (size_t)row * DM;
        float* y = qn + (size_t)row * DM;
        float v1 = x[tid], v2 = x[tid + 256];
        float s = v1 + v2;
        float ss = v1 * v1 + v2 * v2;
        for (int o = 32; o > 0; o >>= 1) { s += __shfl_down(s, o); ss += __shfl_down(ss, o); }
        __shared__ float red[4], red2[4];
        __shared__ float s_mu, s_rstd;
        int wid = tid >> 6, lane = tid & 63;
        if (lane == 0) { red[wid] = s; red2[wid] = ss; }
        __syncthreads();
        if (tid == 0) {
            float ts = red[0] + red[1] + red[2] + red[3];
            float tss = red2[0] + red2[1] + red2[2] + red2[3];
            float mu = ts / DM;
            float var = tss / DM - mu * mu;
            s_mu = mu;
            s_rstd = rsqrtf(var + 1e-6f);
        }
        __syncthreads();
        float mu = s_mu, rstd = s_rstd;
        y[tid]       = (v1 - mu) * rstd * gamma[tid]       + beta[tid];
        y[tid + 256] = (v2 - mu) * rstd * gamma[tid + 256] + beta[tid + 256];
    } else {
        size_t base = ((size_t)(blk - 2304) * 256 + tid) * 4;
        i32x4 dv = *(const i32x4*)(dist + base);
        i32x4 mv = *(const i32x4*)(mask + base);
        unsigned char out[4];
        #pragma unroll
        for (int e = 0; e < 4; ++e) {
            int dc = dv[e]; dc = dc > 5 ? 5 : dc;
            out[e] = (unsigned char)(dc | (mv[e] == 0 ? 8 : 0));
        }
        *(uchar4*)(idxp + base) = *(uchar4*)out;
    }
}

// ---------------- fused q/k/v projection GEMMs (768 blocks) ----------------
__global__ __launch_bounds__(256) void qkv_kernel(
    const float* __restrict__ qn, const float* __restrict__ k, const float* __restrict__ v,
    const short* __restrict__ wT, short* __restrict__ qsb, short* __restrict__ khb,
    short* __restrict__ vT) {
    __shared__ short sA[64 * 64];
    __shared__ short sB[64 * 64];
    int tid = threadIdx.x;
    int sel = blockIdx.x >> 8;
    int t = blockIdx.x & 255;
    int bx = t & 7, by = t >> 3;
    int m0 = by << 6, n0 = bx << 6;
    int w = tid >> 6, l = tid & 63;
    int lr = l & 15, lg = l >> 4;
    const float* A = sel == 0 ? qn : sel == 1 ? k : v;
    const short* Bt = wT + (size_t)sel * 262144;
    float scale = sel == 0 ? 0.125f : 1.0f;
    f32x4 acc[4] = {};
    for (int kt = 0; kt < 512; kt += 64) {
        __syncthreads();
        stage_f32(sA, A + (size_t)m0 * 512 + kt, 512, tid);
        stage_bf16(sB, Bt + (size_t)n0 * 512 + kt, 512, tid);
        __syncthreads();
        mma64(sA, sB, acc, w, lr, lg);
    }
    if (sel == 2) {
        #pragma unroll
        for (int nt = 0; nt < 4; ++nt) {
            int gn = n0 + nt * 16 + lr;
            int gm0 = m0 + w * 16 + lg * 4;
            int bq = gm0 >> 10, j0 = gm0 & 1023;
            int h = gn >> 6, dl = gn & 63;
            bf16x4 pk;
            #pragma unroll
            for (int r = 0; r < 4; ++r) pk[r] = f2b(acc[nt][r]);
            *(bf16x4*)&vT[(((size_t)((bq << 3) + h) << 6) + dl) * 1024 + j0] = pk;
        }
    } else {
        short* C = sel == 0 ? qsb : khb;
        #pragma unroll
        for (int nt = 0; nt < 4; ++nt) {
            #pragma unroll
            for (int r = 0; r < 4; ++r) {
                int gm = m0 + w * 16 + lg * 4 + r;
                int gn = n0 + nt * 16 + lr;
                C[(size_t)gm * 512 + gn] = f2b(acc[nt][r] * scale);
            }
        }
    }
}

// shared prologue for score/pv: stage Q tile, build bias table
static __device__ __forceinline__ void attn_prologue(
    short* sQ, float* sQB, const short* __restrict__ qsb, const float* __restrict__ rpr,
    int b, int h, int i0, int tid) {
    stage_bf16(sQ, qsb + ((size_t)(b * SEQ + i0)) * DM + h * 64, DM, tid);
    __syncthreads();
    for (int item = tid; item < 384; item += 256) {
        int r = item / 6, m = item - r * 6;
        float a = 0.f;
        #pragma unroll 8
        for (int d = 0; d < 64; ++d) a += b2f(sQ[sidx(r, d)]) * rpr[m * 64 + d];
        sQB[r * 8 + m] = a;
    }
    __syncthreads();
}

// ---------------- attention pass 1: l[bh,i,jc] = sum_j exp(s) over 256-j chunk ----------------
__global__ __launch_bounds__(256) void attn_score_kernel(
    const short* __restrict__ qsb, const short* __restrict__ khb,
    const unsigned char* __restrict__ idxp, const float* __restrict__ rpr,
    float* __restrict__ lpart) {
    int bid = blockIdx.x;
    int bh = bid >> 6, rest = bid & 63;
    int it = rest >> 2, jc = rest & 3;
    int b = bh >> 3, h = bh & 7;
    int i0 = it << 6, j0 = jc << 8;
    int tid = threadIdx.x;
    int w = tid >> 6, l = tid & 63;
    int lr = l & 15, lg = l >> 4;

    __shared__ short sQ[64 * 64];
    __shared__ short sK[64 * 64];
    __shared__ float sS[64 * 68];
    __shared__ float sQB[64 * 8];

    attn_prologue(sQ, sQB, qsb, rpr, b, h, i0, tid);

    bf16x8 qf[2];
    qf[0] = *(const bf16x8*)&sQ[sidx(w * 16 + lr, lg * 8)];
    qf[1] = *(const bf16x8*)&sQ[sidx(w * 16 + lr, 32 + lg * 8)];

    int r_ = tid >> 2, c0 = (tid & 3) * 16;
    float lsum = 0.f;

    for (int jt = 0; jt < 4; ++jt) {
        __syncthreads();
        stage_bf16(sK, khb + ((size_t)(b * SEQ + j0 + jt * 64)) * DM + h * 64, DM, tid);
        __syncthreads();
        f32x4 sf[4] = {};
        mma64_score: ;
        #pragma unroll
        for (int ks = 0; ks < 2; ++ks) {
            bf16x8 a = qf[ks];
            #pragma unroll
            for (int nt = 0; nt < 4; ++nt) {
                bf16x8 kf = *(const bf16x8*)&sK[sidx(nt * 16 + lr, ks * 32 + lg * 8)];
                sf[nt] = __builtin_amdgcn_mfma_f32_16x16x32_bf16(a, kf, sf[nt], 0, 0, 0);
            }
        }
        #pragma unroll
        for (int nt = 0; nt < 4; ++nt)
            #pragma unroll
            for (int r = 0; r < 4; ++r)
                sS[(w * 16 + lg * 4 + r) * 68 + nt * 16 + lr] = sf[nt][r];
        __syncthreads();
        const unsigned* ip = (const unsigned*)(idxp + ((size_t)(b * SEQ + i0 + r_)) * SEQ + j0 + jt * 64 + c0);
        #pragma unroll
        for (int g = 0; g < 4; ++g) {
            f32x4 sv = *(const f32x4*)&sS[r_ * 68 + c0 + g * 4];
            unsigned u = ip[g];
            #pragma unroll
            for (int e = 0; e < 4; ++e) {
                unsigned bb = (u >> (8 * e)) & 0xffu;
                float s = fminf(sv[e] + sQB[r_ * 8 + (bb & 7)], 30.f);
                float p = (bb & 8) ? 0.f : __expf(s);
                lsum += p;
            }
        }
    }
    lsum += __shfl_xor(lsum, 1);
    lsum += __shfl_xor(lsum, 2);
    if ((tid & 3) == 0)
        lpart[((size_t)(bh * SEQ + i0 + r_)) * 4 + jc] = lsum;
}

// ---------------- attention pass 2: recompute S, write attn, partial O ----------------
__global__ __launch_bounds__(256) void attn_pv_kernel(
    const short* __restrict__ qsb, const short* __restrict__ khb,
    const unsigned char* __restrict__ idxp, const float* __restrict__ rpr,
    const float* __restrict__ lpart, const short* __restrict__ vT,
    float* __restrict__ attnp, float* __restrict__ Opart) {
    int bid = blockIdx.x;
    int bh = bid >> 6, rest = bid & 63;
    int it = rest >> 2, jc = rest & 3;
    int b = bh >> 3, h = bh & 7;
    int i0 = it << 6, j0 = jc << 8;
    int tid = threadIdx.x;
    int w = tid >> 6, l = tid & 63;
    int lr = l & 15, lg = l >> 4;

    __shared__ short sQ[64 * 64];
    __shared__ short sK[64 * 64];
    __shared__ short sP[64 * 64];
    __shared__ short sV[64 * 64];
    __shared__ float sS[64 * 68];
    __shared__ float sQB[64 * 8];

    attn_prologue(sQ, sQB, qsb, rpr, b, h, i0, tid);

    bf16x8 qf[2];
    qf[0] = *(const bf16x8*)&sQ[sidx(w * 16 + lr, lg * 8)];
    qf[1] = *(const bf16x8*)&sQ[sidx(w * 16 + lr, 32 + lg * 8)];

    int r_ = tid >> 2, c0 = (tid & 3) * 16;
    f32x4 lv = *(const f32x4*)&lpart[((size_t)(bh * SEQ + i0 + r_)) * 4];
    float rl = 1.f / (lv[0] + lv[1] + lv[2] + lv[3]);

    f32x4 oacc[4] = {};
    for (int jt = 0; jt < 4; ++jt) {
        __syncthreads();
        stage_bf16(sK, khb + ((size_t)(b * SEQ + j0 + jt * 64)) * DM + h * 64, DM, tid);
        {   // stage V tile: rows d, cols j
            const short* vsrc = vT + ((size_t)(bh * 64 + r_)) * SEQ + j0 + jt * 64 + c0;
            *(bf16x8*)&sV[sidx(r_, c0)] = *(const bf16x8*)vsrc;
            *(bf16x8*)&sV[sidx(r_, c0 + 8)] = *(const bf16x8*)(vsrc + 8);
        }
        __syncthreads();
        f32x4 sf[4] = {};
        #pragma unroll
        for (int ks = 0; ks < 2; ++ks) {
            bf16x8 a = qf[ks];
            #pragma unroll
            for (int nt = 0; nt < 4; ++nt) {
                bf16x8 kf = *(const bf16x8*)&sK[sidx(nt * 16 + lr, ks * 32 + lg * 8)];
                sf[nt] = __builtin_amdgcn_mfma_f32_16x16x32_bf16(a, kf, sf[nt], 0, 0, 0);
            }
        }
        #pragma unroll
        for (int nt = 0; nt < 4; ++nt)
            #pragma unroll
            for (int r = 0; r < 4; ++r)
                sS[(w * 16 + lg * 4 + r) * 68 + nt * 16 + lr] = sf[nt][r];
        __syncthreads();
        const unsigned* ip = (const unsigned*)(idxp + ((size_t)(b * SEQ + i0 + r_)) * SEQ + j0 + jt * 64 + c0);
        float* arow = attnp + ((size_t)(bh * SEQ + i0 + r_)) * SEQ + j0 + jt * 64 + c0;
        bf16x8 pk[2];
        #pragma unroll
        for (int g = 0; g < 4; ++g) {
            f32x4 sv = *(const f32x4*)&sS[r_ * 68 + c0 + g * 4];
            unsigned u = ip[g];
            f32x4 pv;
            #pragma unroll
            for (int e = 0; e < 4; ++e) {
                unsigned bb = (u >> (8 * e)) & 0xffu;
                float s = fminf(sv[e] + sQB[r_ * 8 + (bb & 7)], 30.f);
                float p = (bb & 8) ? 0.f : __expf(s) * rl;
                pv[e] = p;
                pk[g >> 1][(g & 1) * 4 + e] = f2b(p);
            }
            *(f32x4*)&arow[g * 4] = pv;
        }
        *(bf16x8*)&sP[sidx(r_, c0)] = pk[0];
        *(bf16x8*)&sP[sidx(r_, c0 + 8)] = pk[1];
        __syncthreads();
        mma64(sP, sV, oacc, w, lr, lg);
    }
    float* Ot = Opart + ((size_t)((jc * 16 + bh) * 16 + it)) * 4096;
    #pragma unroll
    for (int nt = 0; nt < 4; ++nt)
        #pragma unroll
        for (int r = 0; r < 4; ++r)
            Ot[(w * 16 + lg * 4 + r) * 64 + nt * 16 + lr] = oacc[nt][r];
}

// ---------------- fc GEMM: out = (sum_jc Opart) @ w_fc^T + q ----------------
__global__ __launch_bounds__(256) void fc_kernel(
    const float* __restrict__ Opart, const short* __restrict__ BtFc,
    const float* __restrict__ Rsd, float* __restrict__ Cp) {
    __shared__ short sA[64 * 64];
    __shared__ short sB[64 * 64];
    int tid = threadIdx.x;
    int bx = blockIdx.x & 7, by = blockIdx.x >> 3;
    int m0 = by << 6, n0 = bx << 6;
    int b = m0 >> 10, it = (m0 & 1023) >> 6;
    int w = tid >> 6, l = tid & 63;
    int lr = l & 15, lg = l >> 4;
    int r_ = tid >> 2, c0 = (tid & 3) * 16;
    f32x4 acc[4] = {};
    for (int kt = 0; kt < 512; kt += 64) {
        int h = kt >> 6;
        __syncthreads();
        {
            const float* base = Opart + ((size_t)((b * 8 + h) * 16 + it)) * 4096 + r_ * 64 + c0;
            f32x4 a0 = {}, a1 = {}, a2 = {}, a3 = {};
            #pragma unroll
            for (int jc = 0; jc < 4; ++jc) {
                const float* p = base + (size_t)jc * 1048576;
                a0 += *(const f32x4*)(p);
                a1 += *(const f32x4*)(p + 4);
                a2 += *(const f32x4*)(p + 8);
                a3 += *(const f32x4*)(p + 12);
            }
            bf16x8 v0, v1;
            #pragma unroll
            for (int e = 0; e < 4; ++e) {
                v0[e] = f2b(a0[e]); v0[4 + e] = f2b(a1[e]);
                v1[e] = f2b(a2[e]); v1[4 + e] = f2b(a3[e]);
            }
            *(bf16x8*)&sA[sidx(r_, c0)] = v0;
            *(bf16x8*)&sA[sidx(r_, c0 + 8)] = v1;
        }
        stage_bf16(sB, BtFc + (size_t)n0 * 512 + kt, 512, tid);
        __syncthreads();
        mma64(sA, sB, acc, w, lr, lg);
    }
    #pragma unroll
    for (int nt = 0; nt < 4; ++nt)
        #pragma unroll
        for (int r = 0; r < 4; ++r) {
            int gm = m0 + w * 16 + lg * 4 + r;
            int gn = n0 + nt * 16 + lr;
            Cp[(size_t)gm * 512 + gn] = acc[nt][r] + Rsd[(size_t)gm * 512 + gn];
        }
}

extern "C" void kernel_launch(void* const* d_in, const int* in_sizes, int n_in,
                              void* d_out, int out_size, void* d_ws, size_t ws_size,
                              hipStream_t stream) {
    const float* q     = (const float*)d_in[0];
    const float* k     = (const float*)d_in[1];
    const float* v     = (const float*)d_in[2];
    const int*   mask  = (const int*)d_in[3];
    const int*   dist  = (const int*)d_in[4];
    const float* w_qs  = (const float*)d_in[5];
    const float* w_ks  = (const float*)d_in[6];
    const float* w_vs  = (const float*)d_in[7];
    const float* w_fc  = (const float*)d_in[8];
    const float* gamma = (const float*)d_in[9];
    const float* beta  = (const float*)d_in[10];
    const float* rpr   = (const float*)d_in[11];

    char* wsb = (char*)d_ws;
    float* Opart = (float*)wsb;                                   // 16MB [0,16M)
    float* qn    = (float*)wsb;                                   // 4MB, dead before Opart written
    short* wT    = (short*)(wsb + 16u * 1024 * 1024);             // 2MB
    short* qsb   = (short*)(wsb + 18u * 1024 * 1024);             // 2MB
    short* khb   = (short*)(wsb + 20u * 1024 * 1024);             // 2MB
    short* vT    = (short*)(wsb + 22u * 1024 * 1024);             // 2MB
    unsigned char* idxp = (unsigned char*)(wsb + 24u * 1024 * 1024); // 2MB
    float* lpart = (float*)(wsb + 26u * 1024 * 1024);             // 256KB

    float* outp  = (float*)d_out;
    float* attnp = outp + 1048576;

    prep_kernel<<<4352, 256, 0, stream>>>(w_qs, w_ks, w_vs, w_fc, wT, q, qn, gamma, beta, dist, mask, idxp);
    qkv_kernel<<<768, 256, 0, stream>>>(qn, k, v, wT, qsb, khb, vT);
    attn_score_kernel<<<1024, 256, 0, stream>>>(qsb, khb, idxp, rpr, lpart);
    attn_pv_kernel<<<1024, 256, 0, stream>>>(qsb, khb, idxp, rpr, lpart, vT, attnp, Opart);
    fc_kernel<<<256, 256, 0, stream>>>(Opart, wT + 786432, q, outp);
}

// Round 4
// 109.030 us; speedup vs baseline: 7.6480x; 1.0910x over previous
//
#include <hip/hip_runtime.h>
#include <math.h>

#define SEQ 1024
#define DM 512

typedef __attribute__((ext_vector_type(8))) short bf16x8;
typedef __attribute__((ext_vector_type(4))) short bf16x4;
typedef __attribute__((ext_vector_type(4))) float f32x4;
typedef __attribute__((ext_vector_type(4))) int i32x4;

static __device__ __forceinline__ short f2b(float f) {
    union { float f; unsigned u; } x; x.f = f;
    unsigned r = (x.u + 0x7FFFu + ((x.u >> 16) & 1u)) >> 16;
    return (short)r;
}
static __device__ __forceinline__ float b2f(short s) {
    union { unsigned u; float f; } x; x.u = ((unsigned)(unsigned short)s) << 16;
    return x.f;
}
// swizzled elem index into a [R][64] bf16 LDS tile (128B rows, XOR bank swizzle)
static __device__ __forceinline__ int sidx(int row, int col) {
    int byte = (row << 7) + (col << 1);
    byte ^= (row & 7) << 4;
    return byte >> 1;
}
// swizzled index into per-wave P strip [16 rows][32 m] bf16 (64B rows)
static __device__ __forceinline__ int spidx(int row, int m) {
    int byte = (row << 6) | (m << 1);
    byte ^= ((row >> 2) & 3) << 4;
    return byte >> 1;
}

static __device__ __forceinline__ void stage_f32(short* dst, const float* src, int srcStride, int tid) {
    int r = tid >> 2, c = (tid & 3) * 16;
    const float* p = src + (size_t)r * srcStride + c;
    bf16x8 v0, v1;
    #pragma unroll
    for (int e = 0; e < 8; ++e) v0[e] = f2b(p[e]);
    #pragma unroll
    for (int e = 0; e < 8; ++e) v1[e] = f2b(p[8 + e]);
    *(bf16x8*)&dst[sidx(r, c)] = v0;
    *(bf16x8*)&dst[sidx(r, c + 8)] = v1;
}
static __device__ __forceinline__ void stage_bf16(short* dst, const short* src, int srcStride, int tid) {
    int r = tid >> 2, c = (tid & 3) * 16;
    const short* p = src + (size_t)r * srcStride + c;
    bf16x8 v0 = *(const bf16x8*)p;
    bf16x8 v1 = *(const bf16x8*)(p + 8);
    *(bf16x8*)&dst[sidx(r, c)] = v0;
    *(bf16x8*)&dst[sidx(r, c + 8)] = v1;
}

// 64x64x64 MFMA block
static __device__ __forceinline__ void mma64(const short* sA, const short* sB, f32x4* acc,
                                             int w, int lr, int lg) {
    #pragma unroll
    for (int ks = 0; ks < 2; ++ks) {
        bf16x8 af = *(const bf16x8*)&sA[sidx(w * 16 + lr, ks * 32 + lg * 8)];
        #pragma unroll
        for (int nt = 0; nt < 4; ++nt) {
            bf16x8 bf = *(const bf16x8*)&sB[sidx(nt * 16 + lr, ks * 32 + lg * 8)];
            acc[nt] = __builtin_amdgcn_mfma_f32_16x16x32_bf16(af, bf, acc[nt], 0, 0, 0);
        }
    }
}

// ---------------- prep: wtrans (256 blk) + layernorm (2048 blk) + idx pack (2048 blk) ----------------
__global__ __launch_bounds__(256) void prep_kernel(
    const float* __restrict__ w0, const float* __restrict__ w1,
    const float* __restrict__ w2, const float* __restrict__ w3, short* __restrict__ wt,
    const float* __restrict__ q, float* __restrict__ qn,
    const float* __restrict__ gamma, const float* __restrict__ beta,
    const int* __restrict__ dist, const int* __restrict__ mask, unsigned char* __restrict__ idxp) {
    int blk = blockIdx.x;
    int tid = threadIdx.x;
    if (blk < 256) {
        int wsel = blk >> 6;
        int t = blk & 63;
        int tr = t >> 3, tc = t & 7;
        const float* src = wsel == 0 ? w0 : wsel == 1 ? w1 : wsel == 2 ? w2 : w3;
        short* dst = wt + (size_t)wsel * 512 * 512;
        __shared__ float tile[64][65];
        int r = tid >> 2, c = (tid & 3) * 16;
        const float* p = src + (size_t)(tr * 64 + r) * 512 + tc * 64 + c;
        #pragma unroll
        for (int e = 0; e < 16; ++e) tile[r][c + e] = p[e];
        __syncthreads();
        bf16x8 v0, v1;
        #pragma unroll
        for (int e = 0; e < 16; ++e) {
            short bv = f2b(tile[c + e][r]);
            if (e < 8) v0[e] = bv; else v1[e - 8] = bv;
        }
        short* qd = dst + (size_t)(tc * 64 + r) * 512 + tr * 64 + c;
        *(bf16x8*)qd = v0;
        *(bf16x8*)(qd + 8) = v1;
    } else if (blk < 2304) {
        int row = blk - 256;
        const float* x = q + (size_t)row * DM;
        float* y = qn + (size_t)row * DM;
        float v1 = x[tid], v2 = x[tid + 256];
        float s = v1 + v2;
        float ss = v1 * v1 + v2 * v2;
        for (int o = 32; o > 0; o >>= 1) { s += __shfl_down(s, o); ss += __shfl_down(ss, o); }
        __shared__ float red[4], red2[4];
        __shared__ float s_mu, s_rstd;
        int wid = tid >> 6, lane = tid & 63;
        if (lane == 0) { red[wid] = s; red2[wid] = ss; }
        __syncthreads();
        if (tid == 0) {
            float ts = red[0] + red[1] + red[2] + red[3];
            float tss = red2[0] + red2[1] + red2[2] + red2[3];
            float mu = ts / DM;
            float var = tss / DM - mu * mu;
            s_mu = mu;
            s_rstd = rsqrtf(var + 1e-6f);
        }
        __syncthreads();
        float mu = s_mu, rstd = s_rstd;
        y[tid]       = (v1 - mu) * rstd * gamma[tid]       + beta[tid];
        y[tid + 256] = (v2 - mu) * rstd * gamma[tid + 256] + beta[tid + 256];
    } else {
        size_t base = ((size_t)(blk - 2304) * 256 + tid) * 4;
        i32x4 dv = *(const i32x4*)(dist + base);
        i32x4 mv = *(const i32x4*)(mask + base);
        unsigned char out[4];
        #pragma unroll
        for (int e = 0; e < 4; ++e) {
            int dc = dv[e]; dc = dc > 5 ? 5 : dc;
            out[e] = (unsigned char)(dc | (mv[e] == 0 ? 8 : 0));
        }
        *(uchar4*)(idxp + base) = *(uchar4*)out;
    }
}

// ---------------- fused q/k/v projection GEMMs (768 blocks) ----------------
__global__ __launch_bounds__(256) void qkv_kernel(
    const float* __restrict__ qn, const float* __restrict__ k, const float* __restrict__ v,
    const short* __restrict__ wT, short* __restrict__ qsb, short* __restrict__ khb,
    short* __restrict__ vT) {
    __shared__ short sA[64 * 64];
    __shared__ short sB[64 * 64];
    int tid = threadIdx.x;
    int sel = blockIdx.x >> 8;
    int t = blockIdx.x & 255;
    int bx = t & 7, by = t >> 3;
    int m0 = by << 6, n0 = bx << 6;
    int w = tid >> 6, l = tid & 63;
    int lr = l & 15, lg = l >> 4;
    const float* A = sel == 0 ? qn : sel == 1 ? k : v;
    const short* Bt = wT + (size_t)sel * 262144;
    float scale = sel == 0 ? 0.125f : 1.0f;
    f32x4 acc[4] = {};
    for (int kt = 0; kt < 512; kt += 64) {
        __syncthreads();
        stage_f32(sA, A + (size_t)m0 * 512 + kt, 512, tid);
        stage_bf16(sB, Bt + (size_t)n0 * 512 + kt, 512, tid);
        __syncthreads();
        mma64(sA, sB, acc, w, lr, lg);
    }
    if (sel == 2) {
        #pragma unroll
        for (int nt = 0; nt < 4; ++nt) {
            int gn = n0 + nt * 16 + lr;
            int gm0 = m0 + w * 16 + lg * 4;
            int bq = gm0 >> 10, j0 = gm0 & 1023;
            int h = gn >> 6, dl = gn & 63;
            bf16x4 pk;
            #pragma unroll
            for (int r = 0; r < 4; ++r) pk[r] = f2b(acc[nt][r]);
            *(bf16x4*)&vT[(((size_t)((bq << 3) + h) << 6) + dl) * 1024 + j0] = pk;
        }
    } else {
        short* C = sel == 0 ? qsb : khb;
        #pragma unroll
        for (int nt = 0; nt < 4; ++nt) {
            #pragma unroll
            for (int r = 0; r < 4; ++r) {
                int gm = m0 + w * 16 + lg * 4 + r;
                int gn = n0 + nt * 16 + lr;
                C[(size_t)gm * 512 + gn] = f2b(acc[nt][r] * scale);
            }
        }
    }
}

// ---------------- single-pass fused attention ----------------
// grid: 16 bh x 64 i-tiles (16 rows). P kept in registers; l computed in-block;
// writes normalized attn + normalized oh. 256 threads = 4 waves, each wave owns
// 16 j-columns per j-tile.
__global__ __launch_bounds__(256) void attn_fused_kernel(
    const short* __restrict__ qsb, const short* __restrict__ khb,
    const short* __restrict__ vT, const unsigned char* __restrict__ idxp,
    const float* __restrict__ rpr, float* __restrict__ attnp, short* __restrict__ oh) {
    int bid = blockIdx.x;
    int bh = bid >> 6, it = bid & 63;
    int b = bh >> 3, h = bh & 7;
    int i0 = it << 4;
    int tid = threadIdx.x;
    int w = tid >> 6, l = tid & 63;
    int lr = l & 15, lg = l >> 4;

    __shared__ short sQ[16 * 64];
    __shared__ short sK[2 * 64 * 64];      // 16KB; reused as sO (f32 [4][16][64]) in epilogue
    __shared__ short sPw[4 * 512];         // per-wave P strip [16][32]
    __shared__ float sQB[16 * 8];
    __shared__ float sL[4][16];
    __shared__ float sRl[16];
    float* sO = (float*)sK;

    // stage Q (16x64) + first K tile
    if (tid < 128) {
        int r = tid >> 3, c = (tid & 7) * 8;
        bf16x8 qv = *(const bf16x8*)(qsb + ((size_t)(b * SEQ + i0 + r)) * DM + h * 64 + c);
        *(bf16x8*)&sQ[sidx(r, c)] = qv;
    }
    stage_bf16(sK, khb + ((size_t)(b * SEQ)) * DM + h * 64, DM, tid);
    __syncthreads();
    // bias table: sQB[row][m] = sum_d qs[row][d] * rpr[m][d]
    if (tid < 128) {
        int r = tid >> 3, m = tid & 7;
        if (m < 6) {
            float a = 0.f;
            #pragma unroll 8
            for (int d = 0; d < 64; ++d) a += b2f(sQ[sidx(r, d)]) * rpr[m * 64 + d];
            sQB[r * 8 + m] = a;
        }
    }
    __syncthreads();

    bf16x8 qf0 = *(const bf16x8*)&sQ[sidx(lr, lg * 8)];
    bf16x8 qf1 = *(const bf16x8*)&sQ[sidx(lr, 32 + lg * 8)];

    float l_acc[4] = {0.f, 0.f, 0.f, 0.f};
    unsigned p_lo[16], p_hi[16];
    f32x4 accO[4] = {};
    const unsigned char* ib = idxp + ((size_t)(b * SEQ + i0)) * SEQ;
    short* pw = sPw + w * 512;
    const short* vbase = vT + ((size_t)(bh * 64)) * 1024;

    #pragma unroll
    for (int jt = 0; jt < 16; ++jt) {
        int buf = (jt & 1) * 4096;
        if (jt < 15)
            stage_bf16(sK + (buf ^ 4096), khb + ((size_t)(b * SEQ + (jt + 1) * 64)) * DM + h * 64, DM, tid);
        // QK^T: this wave's 16 cols (j = jt*64 + w*16 + lr)
        bf16x8 kf0 = *(const bf16x8*)&sK[buf + sidx(w * 16 + lr, lg * 8)];
        bf16x8 kf1 = *(const bf16x8*)&sK[buf + sidx(w * 16 + lr, 32 + lg * 8)];
        f32x4 sf = {};
        sf = __builtin_amdgcn_mfma_f32_16x16x32_bf16(qf0, kf0, sf, 0, 0, 0);
        sf = __builtin_amdgcn_mfma_f32_16x16x32_bf16(qf1, kf1, sf, 0, 0, 0);
        // bias + exp (acc layout: lane owns col jcol, rows lg*4+r)
        int jcol = jt * 64 + w * 16 + lr;
        float pv[4];
        #pragma unroll
        for (int r = 0; r < 4; ++r) {
            unsigned bb = ib[(size_t)(lg * 4 + r) * SEQ + jcol];
            float s = fminf(sf[r] + sQB[(lg * 4 + r) * 8 + (bb & 7)], 30.f);
            float p = (bb & 8) ? 0.f : __expf(s);
            pv[r] = p;
            l_acc[r] += p;
        }
        unsigned plo = (unsigned)(unsigned short)f2b(pv[0]) | ((unsigned)(unsigned short)f2b(pv[1]) << 16);
        unsigned phi = (unsigned)(unsigned short)f2b(pv[2]) | ((unsigned)(unsigned short)f2b(pv[3]) << 16);
        p_lo[jt] = plo; p_hi[jt] = phi;
        // stash P into wave-local strip for PV A-fragment (m = (jt&1)*16 + lr)
        int m = (jt & 1) * 16 + lr;
        pw[spidx(lg * 4 + 0, m)] = (short)(plo & 0xffff);
        pw[spidx(lg * 4 + 1, m)] = (short)(plo >> 16);
        pw[spidx(lg * 4 + 2, m)] = (short)(phi & 0xffff);
        pw[spidx(lg * 4 + 3, m)] = (short)(phi >> 16);
        if (jt & 1) {
            // PV over pair (jt-1, jt): k=32, j(m') = (jt-1 + (m'>>4))*64 + w*16 + (m'&15)
            int jt0 = jt - 1;
            bf16x8 af = *(const bf16x8*)&pw[spidx(lr, lg * 8)];
            int jb = jt0 * 64 + (lg >> 1) * 64 + w * 16 + (lg & 1) * 8;
            #pragma unroll
            for (int nt = 0; nt < 4; ++nt) {
                bf16x8 bf = *(const bf16x8*)(vbase + (size_t)(nt * 16 + lr) * 1024 + jb);
                accO[nt] = __builtin_amdgcn_mfma_f32_16x16x32_bf16(af, bf, accO[nt], 0, 0, 0);
            }
        }
        __syncthreads();
    }

    // row-sum reduce: over lr within wave, then across waves
    #pragma unroll
    for (int r = 0; r < 4; ++r) {
        float s = l_acc[r];
        s += __shfl_xor(s, 1); s += __shfl_xor(s, 2);
        s += __shfl_xor(s, 4); s += __shfl_xor(s, 8);
        l_acc[r] = s;
    }
    if (lr == 0) {
        #pragma unroll
        for (int r = 0; r < 4; ++r) sL[w][lg * 4 + r] = l_acc[r];
    }
    __syncthreads();
    if (tid < 16) {
        float t = sL[0][tid] + sL[1][tid] + sL[2][tid] + sL[3][tid];
        sRl[tid] = 1.f / t;
    }
    // O partials into sO (sK space; all sK reads completed before last barrier)
    #pragma unroll
    for (int nt = 0; nt < 4; ++nt)
        #pragma unroll
        for (int r = 0; r < 4; ++r)
            sO[(w * 16 + lg * 4 + r) * 64 + nt * 16 + lr] = accO[nt][r];
    __syncthreads();

    // reduce O across waves, normalize, write oh
    {
        int row = tid >> 4, c4 = (tid & 15) * 4;
        f32x4 o = *(f32x4*)&sO[(0 * 16 + row) * 64 + c4];
        o += *(f32x4*)&sO[(1 * 16 + row) * 64 + c4];
        o += *(f32x4*)&sO[(2 * 16 + row) * 64 + c4];
        o += *(f32x4*)&sO[(3 * 16 + row) * 64 + c4];
        float rl = sRl[row];
        bf16x4 ob;
        #pragma unroll
        for (int e = 0; e < 4; ++e) ob[e] = f2b(o[e] * rl);
        *(bf16x4*)&oh[((size_t)(b * SEQ + i0 + row)) * DM + h * 64 + c4] = ob;
    }

    // write normalized attn from registers
    float rla[4];
    #pragma unroll
    for (int r = 0; r < 4; ++r) rla[r] = sRl[lg * 4 + r];
    float* ap = attnp + ((size_t)(bh * SEQ + i0 + lg * 4)) * SEQ + w * 16 + lr;
    #pragma unroll
    for (int jt = 0; jt < 16; ++jt) {
        unsigned plo = p_lo[jt], phi = p_hi[jt];
        ap[(size_t)0 * SEQ + jt * 64] = b2f((short)(plo & 0xffff)) * rla[0];
        ap[(size_t)1 * SEQ + jt * 64] = b2f((short)(plo >> 16))    * rla[1];
        ap[(size_t)2 * SEQ + jt * 64] = b2f((short)(phi & 0xffff)) * rla[2];
        ap[(size_t)3 * SEQ + jt * 64] = b2f((short)(phi >> 16))    * rla[3];
    }
}

// ---------------- fc GEMM: out = oh @ w_fc^T + q ----------------
__global__ __launch_bounds__(256) void fc_kernel(
    const short* __restrict__ oh, const short* __restrict__ BtFc,
    const float* __restrict__ Rsd, float* __restrict__ Cp) {
    __shared__ short sA[64 * 64];
    __shared__ short sB[64 * 64];
    int tid = threadIdx.x;
    int bx = blockIdx.x & 7, by = blockIdx.x >> 3;
    int m0 = by << 6, n0 = bx << 6;
    int w = tid >> 6, l = tid & 63;
    int lr = l & 15, lg = l >> 4;
    f32x4 acc[4] = {};
    for (int kt = 0; kt < 512; kt += 64) {
        __syncthreads();
        stage_bf16(sA, oh + (size_t)m0 * 512 + kt, 512, tid);
        stage_bf16(sB, BtFc + (size_t)n0 * 512 + kt, 512, tid);
        __syncthreads();
        mma64(sA, sB, acc, w, lr, lg);
    }
    #pragma unroll
    for (int nt = 0; nt < 4; ++nt)
        #pragma unroll
        for (int r = 0; r < 4; ++r) {
            int gm = m0 + w * 16 + lg * 4 + r;
            int gn = n0 + nt * 16 + lr;
            Cp[(size_t)gm * 512 + gn] = acc[nt][r] + Rsd[(size_t)gm * 512 + gn];
        }
}

extern "C" void kernel_launch(void* const* d_in, const int* in_sizes, int n_in,
                              void* d_out, int out_size, void* d_ws, size_t ws_size,
                              hipStream_t stream) {
    const float* q     = (const float*)d_in[0];
    const float* k     = (const float*)d_in[1];
    const float* v     = (const float*)d_in[2];
    const int*   mask  = (const int*)d_in[3];
    const int*   dist  = (const int*)d_in[4];
    const float* w_qs  = (const float*)d_in[5];
    const float* w_ks  = (const float*)d_in[6];
    const float* w_vs  = (const float*)d_in[7];
    const float* w_fc  = (const float*)d_in[8];
    const float* gamma = (const float*)d_in[9];
    const float* beta  = (const float*)d_in[10];
    const float* rpr   = (const float*)d_in[11];

    char* wsb = (char*)d_ws;
    float* qn   = (float*)wsb;                                   // 4MB (dead after qkv)
    short* oh   = (short*)wsb;                                   // 2MB, overlays qn
    short* wT   = (short*)(wsb + 4u * 1024 * 1024);              // 2MB
    short* qsb  = (short*)(wsb + 6u * 1024 * 1024);              // 2MB
    short* khb  = (short*)(wsb + 8u * 1024 * 1024);              // 2MB
    short* vT   = (short*)(wsb + 10u * 1024 * 1024);             // 2MB
    unsigned char* idxp = (unsigned char*)(wsb + 12u * 1024 * 1024); // 2MB

    float* outp  = (float*)d_out;
    float* attnp = outp + 1048576;

    prep_kernel<<<4352, 256, 0, stream>>>(w_qs, w_ks, w_vs, w_fc, wT, q, qn, gamma, beta, dist, mask, idxp);
    qkv_kernel<<<768, 256, 0, stream>>>(qn, k, v, wT, qsb, khb, vT);
    attn_fused_kernel<<<1024, 256, 0, stream>>>(qsb, khb, vT, idxp, rpr, attnp, oh);
    fc_kernel<<<256, 256, 0, stream>>>(oh, wT + 786432, q, outp);
}

// Round 6
// 82.152 us; speedup vs baseline: 10.1502x; 1.3272x over previous
//
#include <hip/hip_runtime.h>
#include <math.h>

#define SEQ 1024
#define DM 512

typedef __attribute__((ext_vector_type(8))) short bf16x8;
typedef __attribute__((ext_vector_type(4))) short bf16x4;
typedef __attribute__((ext_vector_type(4))) float f32x4;
typedef __attribute__((ext_vector_type(4))) int i32x4;

static __device__ __forceinline__ short f2b(float f) {
    union { float f; unsigned u; } x; x.f = f;
    unsigned r = (x.u + 0x7FFFu + ((x.u >> 16) & 1u)) >> 16;
    return (short)r;
}
static __device__ __forceinline__ float b2f(short s) {
    union { unsigned u; float f; } x; x.u = ((unsigned)(unsigned short)s) << 16;
    return x.f;
}
// swizzled elem index into a [R][64] bf16 LDS tile (128B rows, XOR bank swizzle)
static __device__ __forceinline__ int sidx(int row, int col) {
    int byte = (row << 7) + (col << 1);
    byte ^= (row & 7) << 4;
    return byte >> 1;
}
// swizzled index into per-wave P strip [16 rows][32 m] bf16 (64B rows)
static __device__ __forceinline__ int spidx(int row, int m) {
    int byte = (row << 6) | (m << 1);
    byte ^= ((row >> 2) & 3) << 4;
    return byte >> 1;
}

static __device__ __forceinline__ void stage_f32(short* dst, const float* src, int srcStride, int tid) {
    int r = tid >> 2, c = (tid & 3) * 16;
    const float* p = src + (size_t)r * srcStride + c;
    bf16x8 v0, v1;
    #pragma unroll
    for (int e = 0; e < 8; ++e) v0[e] = f2b(p[e]);
    #pragma unroll
    for (int e = 0; e < 8; ++e) v1[e] = f2b(p[8 + e]);
    *(bf16x8*)&dst[sidx(r, c)] = v0;
    *(bf16x8*)&dst[sidx(r, c + 8)] = v1;
}
static __device__ __forceinline__ void stage_bf16(short* dst, const short* src, int srcStride, int tid) {
    int r = tid >> 2, c = (tid & 3) * 16;
    const short* p = src + (size_t)r * srcStride + c;
    bf16x8 v0 = *(const bf16x8*)p;
    bf16x8 v1 = *(const bf16x8*)(p + 8);
    *(bf16x8*)&dst[sidx(r, c)] = v0;
    *(bf16x8*)&dst[sidx(r, c + 8)] = v1;
}

// 64x64x64 MFMA block
static __device__ __forceinline__ void mma64(const short* sA, const short* sB, f32x4* acc,
                                             int w, int lr, int lg) {
    #pragma unroll
    for (int ks = 0; ks < 2; ++ks) {
        bf16x8 af = *(const bf16x8*)&sA[sidx(w * 16 + lr, ks * 32 + lg * 8)];
        #pragma unroll
        for (int nt = 0; nt < 4; ++nt) {
            bf16x8 bf = *(const bf16x8*)&sB[sidx(nt * 16 + lr, ks * 32 + lg * 8)];
            acc[nt] = __builtin_amdgcn_mfma_f32_16x16x32_bf16(af, bf, acc[nt], 0, 0, 0);
        }
    }
}

// ---------------- prep: wtrans (256 blk) + layernorm (2048 blk) + idx pack (2048 blk) ----------------
__global__ __launch_bounds__(256) void prep_kernel(
    const float* __restrict__ w0, const float* __restrict__ w1,
    const float* __restrict__ w2, const float* __restrict__ w3, short* __restrict__ wt,
    const float* __restrict__ q, float* __restrict__ qn,
    const float* __restrict__ gamma, const float* __restrict__ beta,
    const int* __restrict__ dist, const int* __restrict__ mask, unsigned char* __restrict__ idxp) {
    int blk = blockIdx.x;
    int tid = threadIdx.x;
    if (blk < 256) {
        int wsel = blk >> 6;
        int t = blk & 63;
        int tr = t >> 3, tc = t & 7;
        const float* src = wsel == 0 ? w0 : wsel == 1 ? w1 : wsel == 2 ? w2 : w3;
        short* dst = wt + (size_t)wsel * 512 * 512;
        __shared__ float tile[64][65];
        int r = tid >> 2, c = (tid & 3) * 16;
        const float* p = src + (size_t)(tr * 64 + r) * 512 + tc * 64 + c;
        #pragma unroll
        for (int e = 0; e < 16; ++e) tile[r][c + e] = p[e];
        __syncthreads();
        bf16x8 v0, v1;
        #pragma unroll
        for (int e = 0; e < 16; ++e) {
            short bv = f2b(tile[c + e][r]);
            if (e < 8) v0[e] = bv; else v1[e - 8] = bv;
        }
        short* qd = dst + (size_t)(tc * 64 + r) * 512 + tr * 64 + c;
        *(bf16x8*)qd = v0;
        *(bf16x8*)(qd + 8) = v1;
    } else if (blk < 2304) {
        int row = blk - 256;
        const float* x = q + (size_t)row * DM;
        float* y = qn + (size_t)row * DM;
        float v1 = x[tid], v2 = x[tid + 256];
        float s = v1 + v2;
        float ss = v1 * v1 + v2 * v2;
        for (int o = 32; o > 0; o >>= 1) { s += __shfl_down(s, o); ss += __shfl_down(ss, o); }
        __shared__ float red[4], red2[4];
        __shared__ float s_mu, s_rstd;
        int wid = tid >> 6, lane = tid & 63;
        if (lane == 0) { red[wid] = s; red2[wid] = ss; }
        __syncthreads();
        if (tid == 0) {
            float ts = red[0] + red[1] + red[2] + red[3];
            float tss = red2[0] + red2[1] + red2[2] + red2[3];
            float mu = ts / DM;
            float var = tss / DM - mu * mu;
            s_mu = mu;
            s_rstd = rsqrtf(var + 1e-6f);
        }
        __syncthreads();
        float mu = s_mu, rstd = s_rstd;
        y[tid]       = (v1 - mu) * rstd * gamma[tid]       + beta[tid];
        y[tid + 256] = (v2 - mu) * rstd * gamma[tid + 256] + beta[tid + 256];
    } else {
        size_t base = ((size_t)(blk - 2304) * 256 + tid) * 4;
        i32x4 dv = *(const i32x4*)(dist + base);
        i32x4 mv = *(const i32x4*)(mask + base);
        unsigned char out[4];
        #pragma unroll
        for (int e = 0; e < 4; ++e) {
            int dc = dv[e]; dc = dc > 5 ? 5 : dc;
            out[e] = (unsigned char)(dc | (mv[e] == 0 ? 8 : 0));
        }
        *(uchar4*)(idxp + base) = *(uchar4*)out;
    }
}

// ---------------- fused q/k/v projection GEMMs (768 blocks) ----------------
__global__ __launch_bounds__(256) void qkv_kernel(
    const float* __restrict__ qn, const float* __restrict__ k, const float* __restrict__ v,
    const short* __restrict__ wT, short* __restrict__ qsb, short* __restrict__ khb,
    short* __restrict__ vT) {
    __shared__ short sA[64 * 64];
    __shared__ short sB[64 * 64];
    int tid = threadIdx.x;
    int sel = blockIdx.x >> 8;
    int t = blockIdx.x & 255;
    int bx = t & 7, by = t >> 3;
    int m0 = by << 6, n0 = bx << 6;
    int w = tid >> 6, l = tid & 63;
    int lr = l & 15, lg = l >> 4;
    const float* A = sel == 0 ? qn : sel == 1 ? k : v;
    const short* Bt = wT + (size_t)sel * 262144;
    float scale = sel == 0 ? 0.125f : 1.0f;
    f32x4 acc[4] = {};
    for (int kt = 0; kt < 512; kt += 64) {
        __syncthreads();
        stage_f32(sA, A + (size_t)m0 * 512 + kt, 512, tid);
        stage_bf16(sB, Bt + (size_t)n0 * 512 + kt, 512, tid);
        __syncthreads();
        mma64(sA, sB, acc, w, lr, lg);
    }
    if (sel == 2) {
        #pragma unroll
        for (int nt = 0; nt < 4; ++nt) {
            int gn = n0 + nt * 16 + lr;
            int gm0 = m0 + w * 16 + lg * 4;
            int bq = gm0 >> 10, j0 = gm0 & 1023;
            int h = gn >> 6, dl = gn & 63;
            bf16x4 pk;
            #pragma unroll
            for (int r = 0; r < 4; ++r) pk[r] = f2b(acc[nt][r]);
            *(bf16x4*)&vT[(((size_t)((bq << 3) + h) << 6) + dl) * 1024 + j0] = pk;
        }
    } else {
        short* C = sel == 0 ? qsb : khb;
        #pragma unroll
        for (int nt = 0; nt < 4; ++nt) {
            #pragma unroll
            for (int r = 0; r < 4; ++r) {
                int gm = m0 + w * 16 + lg * 4 + r;
                int gn = n0 + nt * 16 + lr;
                C[(size_t)gm * 512 + gn] = f2b(acc[nt][r] * scale);
            }
        }
    }
}

// ---------------- single-pass fused attention, barrier-free main loop ----------------
// grid: 16 bh x 64 i-tiles (16 rows). K and V fragments loaded directly from
// global (L2-resident panels) into registers; P kept in registers + wave-private
// LDS strip. No __syncthreads in the j-sweep.
__global__ __launch_bounds__(256) void attn_fused_kernel(
    const short* __restrict__ qsb, const short* __restrict__ khb,
    const short* __restrict__ vT, const unsigned char* __restrict__ idxp,
    const float* __restrict__ rpr, float* __restrict__ attnp, short* __restrict__ oh) {
    int bid = blockIdx.x;
    int bh = bid >> 6, it = bid & 63;
    int b = bh >> 3, h = bh & 7;
    int i0 = it << 4;
    int tid = threadIdx.x;
    int w = tid >> 6, l = tid & 63;
    int lr = l & 15, lg = l >> 4;

    __shared__ short sQ[16 * 64];
    __shared__ short sPw[4 * 512];         // per-wave P strip [16][32]
    __shared__ float sQB[16 * 8];
    __shared__ float sL[4][16];
    __shared__ float sO[64 * 64];          // [4 waves][16 rows][64 cols] f32 partials

    // stage Q (16x64)
    if (tid < 128) {
        int r = tid >> 3, c = (tid & 7) * 8;
        bf16x8 qv = *(const bf16x8*)(qsb + ((size_t)(b * SEQ + i0 + r)) * DM + h * 64 + c);
        *(bf16x8*)&sQ[sidx(r, c)] = qv;
    }
    __syncthreads();
    // bias table: sQB[row][m] = sum_d qs[row][d] * rpr[m][d]
    if (tid < 128) {
        int r = tid >> 3, m = tid & 7;
        if (m < 6) {
            float a = 0.f;
            #pragma unroll 8
            for (int d = 0; d < 64; ++d) a += b2f(sQ[sidx(r, d)]) * rpr[m * 64 + d];
            sQB[r * 8 + m] = a;
        }
    }
    __syncthreads();

    bf16x8 qf0 = *(const bf16x8*)&sQ[sidx(lr, lg * 8)];
    bf16x8 qf1 = *(const bf16x8*)&sQ[sidx(lr, 32 + lg * 8)];

    float l_acc[4] = {0.f, 0.f, 0.f, 0.f};
    unsigned p_lo[16], p_hi[16];
    f32x4 accO[4] = {};
    const unsigned char* ib = idxp + ((size_t)(b * SEQ + i0)) * SEQ;
    short* pw = sPw + w * 512;
    const short* vbase = vT + ((size_t)(bh * 64)) * 1024;
    const short* kbase = khb + ((size_t)(b * SEQ)) * DM + h * 64 + lg * 8;

    #pragma unroll
    for (int jt = 0; jt < 16; ++jt) {
        // K fragments direct from global: row j = jt*64 + w*16 + lr, cols lg*8(+32)
        const short* kp = kbase + (size_t)(jt * 64 + w * 16 + lr) * DM;
        bf16x8 kf0 = *(const bf16x8*)kp;
        bf16x8 kf1 = *(const bf16x8*)(kp + 32);
        f32x4 sf = {};
        sf = __builtin_amdgcn_mfma_f32_16x16x32_bf16(qf0, kf0, sf, 0, 0, 0);
        sf = __builtin_amdgcn_mfma_f32_16x16x32_bf16(qf1, kf1, sf, 0, 0, 0);
        // bias + exp (acc layout: lane owns col jcol, rows lg*4+r)
        int jcol = jt * 64 + w * 16 + lr;
        float pv[4];
        #pragma unroll
        for (int r = 0; r < 4; ++r) {
            unsigned bb = ib[(size_t)(lg * 4 + r) * SEQ + jcol];
            float s = fminf(sf[r] + sQB[(lg * 4 + r) * 8 + (bb & 7)], 30.f);
            float p = (bb & 8) ? 0.f : __expf(s);
            pv[r] = p;
            l_acc[r] += p;
        }
        unsigned plo = (unsigned)(unsigned short)f2b(pv[0]) | ((unsigned)(unsigned short)f2b(pv[1]) << 16);
        unsigned phi = (unsigned)(unsigned short)f2b(pv[2]) | ((unsigned)(unsigned short)f2b(pv[3]) << 16);
        p_lo[jt] = plo; p_hi[jt] = phi;
        // stash P into wave-local strip for PV A-fragment (m = (jt&1)*16 + lr)
        int m = (jt & 1) * 16 + lr;
        pw[spidx(lg * 4 + 0, m)] = (short)(plo & 0xffff);
        pw[spidx(lg * 4 + 1, m)] = (short)(plo >> 16);
        pw[spidx(lg * 4 + 2, m)] = (short)(phi & 0xffff);
        pw[spidx(lg * 4 + 3, m)] = (short)(phi >> 16);
        if (jt & 1) {
            // PV over pair (jt-1, jt): k=32, j(m') = (jt-1 + (m'>>4))*64 + w*16 + (m'&15)
            int jt0 = jt - 1;
            bf16x8 af = *(const bf16x8*)&pw[spidx(lr, lg * 8)];
            int jb = jt0 * 64 + (lg >> 1) * 64 + w * 16 + (lg & 1) * 8;
            #pragma unroll
            for (int nt = 0; nt < 4; ++nt) {
                bf16x8 bf = *(const bf16x8*)(vbase + (size_t)(nt * 16 + lr) * 1024 + jb);
                accO[nt] = __builtin_amdgcn_mfma_f32_16x16x32_bf16(af, bf, accO[nt], 0, 0, 0);
            }
        }
    }

    // row-sum reduce over lr within wave
    #pragma unroll
    for (int r = 0; r < 4; ++r) {
        float s = l_acc[r];
        s += __shfl_xor(s, 1); s += __shfl_xor(s, 2);
        s += __shfl_xor(s, 4); s += __shfl_xor(s, 8);
        l_acc[r] = s;
    }
    if (lr == 0) {
        #pragma unroll
        for (int r = 0; r < 4; ++r) sL[w][lg * 4 + r] = l_acc[r];
    }
    // O partials: wave w owns rows [w*16, w*16+16) of the [64][64] partial array
    #pragma unroll
    for (int nt = 0; nt < 4; ++nt)
        #pragma unroll
        for (int r = 0; r < 4; ++r)
            sO[(w * 16 + lg * 4 + r) * 64 + nt * 16 + lr] = accO[nt][r];
    __syncthreads();

    // reduce O across waves, normalize, write oh
    {
        int row = tid >> 4, c4 = (tid & 15) * 4;
        f32x4 o = *(f32x4*)&sO[(0 * 16 + row) * 64 + c4];
        o += *(f32x4*)&sO[(1 * 16 + row) * 64 + c4];
        o += *(f32x4*)&sO[(2 * 16 + row) * 64 + c4];
        o += *(f32x4*)&sO[(3 * 16 + row) * 64 + c4];
        float rl = 1.f / (sL[0][row] + sL[1][row] + sL[2][row] + sL[3][row]);
        bf16x4 ob;
        #pragma unroll
        for (int e = 0; e < 4; ++e) ob[e] = f2b(o[e] * rl);
        *(bf16x4*)&oh[((size_t)(b * SEQ + i0 + row)) * DM + h * 64 + c4] = ob;
    }

    // write normalized attn from registers
    float rla[4];
    #pragma unroll
    for (int r = 0; r < 4; ++r) {
        int row = lg * 4 + r;
        rla[r] = 1.f / (sL[0][row] + sL[1][row] + sL[2][row] + sL[3][row]);
    }
    float* ap = attnp + ((size_t)(bh * SEQ + i0 + lg * 4)) * SEQ + w * 16 + lr;
    #pragma unroll
    for (int jt = 0; jt < 16; ++jt) {
        unsigned plo = p_lo[jt], phi = p_hi[jt];
        ap[(size_t)0 * SEQ + jt * 64] = b2f((short)(plo & 0xffff)) * rla[0];
        ap[(size_t)1 * SEQ + jt * 64] = b2f((short)(plo >> 16))    * rla[1];
        ap[(size_t)2 * SEQ + jt * 64] = b2f((short)(phi & 0xffff)) * rla[2];
        ap[(size_t)3 * SEQ + jt * 64] = b2f((short)(phi >> 16))    * rla[3];
    }
}

// ---------------- fc GEMM: out = oh @ w_fc^T + q ----------------
__global__ __launch_bounds__(256) void fc_kernel(
    const short* __restrict__ oh, const short* __restrict__ BtFc,
    const float* __restrict__ Rsd, float* __restrict__ Cp) {
    __shared__ short sA[64 * 64];
    __shared__ short sB[64 * 64];
    int tid = threadIdx.x;
    int bx = blockIdx.x & 7, by = blockIdx.x >> 3;
    int m0 = by << 6, n0 = bx << 6;
    int w = tid >> 6, l = tid & 63;
    int lr = l & 15, lg = l >> 4;
    f32x4 acc[4] = {};
    for (int kt = 0; kt < 512; kt += 64) {
        __syncthreads();
        stage_bf16(sA, oh + (size_t)m0 * 512 + kt, 512, tid);
        stage_bf16(sB, BtFc + (size_t)n0 * 512 + kt, 512, tid);
        __syncthreads();
        mma64(sA, sB, acc, w, lr, lg);
    }
    #pragma unroll
    for (int nt = 0; nt < 4; ++nt)
        #pragma unroll
        for (int r = 0; r < 4; ++r) {
            int gm = m0 + w * 16 + lg * 4 + r;
            int gn = n0 + nt * 16 + lr;
            Cp[(size_t)gm * 512 + gn] = acc[nt][r] + Rsd[(size_t)gm * 512 + gn];
        }
}

extern "C" void kernel_launch(void* const* d_in, const int* in_sizes, int n_in,
                              void* d_out, int out_size, void* d_ws, size_t ws_size,
                              hipStream_t stream) {
    const float* q     = (const float*)d_in[0];
    const float* k     = (const float*)d_in[1];
    const float* v     = (const float*)d_in[2];
    const int*   mask  = (const int*)d_in[3];
    const int*   dist  = (const int*)d_in[4];
    const float* w_qs  = (const float*)d_in[5];
    const float* w_ks  = (const float*)d_in[6];
    const float* w_vs  = (const float*)d_in[7];
    const float* w_fc  = (const float*)d_in[8];
    const float* gamma = (const float*)d_in[9];
    const float* beta  = (const float*)d_in[10];
    const float* rpr   = (const float*)d_in[11];

    char* wsb = (char*)d_ws;
    float* qn   = (float*)wsb;                                   // 4MB (dead after qkv)
    short* oh   = (short*)wsb;                                   // 2MB, overlays qn
    short* wT   = (short*)(wsb + 4u * 1024 * 1024);              // 2MB
    short* qsb  = (short*)(wsb + 6u * 1024 * 1024);              // 2MB
    short* khb  = (short*)(wsb + 8u * 1024 * 1024);              // 2MB
    short* vT   = (short*)(wsb + 10u * 1024 * 1024);             // 2MB
    unsigned char* idxp = (unsigned char*)(wsb + 12u * 1024 * 1024); // 2MB

    float* outp  = (float*)d_out;
    float* attnp = outp + 1048576;

    prep_kernel<<<4352, 256, 0, stream>>>(w_qs, w_ks, w_vs, w_fc, wT, q, qn, gamma, beta, dist, mask, idxp);
    qkv_kernel<<<768, 256, 0, stream>>>(qn, k, v, wT, qsb, khb, vT);
    attn_fused_kernel<<<1024, 256, 0, stream>>>(qsb, khb, vT, idxp, rpr, attnp, oh);
    fc_kernel<<<256, 256, 0, stream>>>(oh, wT + 786432, q, outp);
}